// Round 3
// baseline (145.144 us; speedup 1.0000x reference)
//
#include <hip/hip_runtime.h>

// Problem constants (reference: B=8, N=4096, F=1024, C=64)
#define B_   8
#define N_   4096
#define F_   1024
#define C_   64
#define TN   64           // rows per block tile
#define KC   64           // K (f) chunk per staging iteration
#define NB   (N_ / TN)    // 64 row-tiles per (input,batch)
#define MARGIN 0.02f      // >= 100x the bf16-split score error bound (~5e-5)

typedef __attribute__((ext_vector_type(8))) short bhalf8;   // 8 bf16 = 4 VGPRs (MFMA A/B frag)
typedef __attribute__((ext_vector_type(4))) float f32x4;    // MFMA C/D frag
typedef __attribute__((ext_vector_type(4))) unsigned short us4;

__device__ __forceinline__ unsigned short f2bf_rne(float x) {
    unsigned u = __builtin_bit_cast(unsigned, x);
    u += 0x7fffu + ((u >> 16) & 1u);          // round-to-nearest-even
    return (unsigned short)(u >> 16);
}
__device__ __forceinline__ float bf2f(unsigned short h) {
    unsigned u = ((unsigned)h) << 16;
    return __builtin_bit_cast(float, u);
}

#define LEXGT(a, ai, b, bi) ((a) > (b) || ((a) == (b) && (ai) < (bi)))
// insert (vv,nn) into sorted top-2 (v0,i0)>=(v1,i1)
#define INSERT2(vv, nn)                                                   \
    do {                                                                  \
        float _v = (vv); int _n = (nn);                                   \
        if (LEXGT(_v, _n, v0, i0)) { v1=v0; i1=i0; v0=_v; i0=_n; }        \
        else if (LEXGT(_v, _n, v1, i1)) { v1=_v; i1=_n; }                 \
    } while (0)

// K0: convert W (fp32 [64][1024]) to bf16 hi/lo planes in workspace.
__global__ __launch_bounds__(256) void wconv_kernel(
    const float* __restrict__ W,
    unsigned short* __restrict__ Wh, unsigned short* __restrict__ Wl)
{
    int i = blockIdx.x * 256 + threadIdx.x;        // 16384 float4s total
    float4 v = ((const float4*)W)[i];
    float f[4] = {v.x, v.y, v.z, v.w};
    us4 hh, ll;
    #pragma unroll
    for (int e = 0; e < 4; ++e) {
        unsigned short h = f2bf_rne(f[e]);
        hh[e] = h;
        ll[e] = f2bf_rne(f[e] - bf2f(h));
    }
    ((us4*)Wh)[i] = hh;
    ((us4*)Wl)[i] = ll;
}

// K1: bf16-split MFMA GEMM (scores = x @ W^T), fused per-block per-class top-2.
// Block: 64 rows x 64 classes, 4 waves; wave w owns rows w*16..w*16+15 (1 m-tile),
// all 4 n-tiles. X staged in LDS (hi/lo planes, XOR-swizzled); W fragments read
// directly from preconverted global bf16 planes (L1/L2-resident, 16 KB/chunk).
// Pipeline: convert(kc) -> barrier -> A ds_reads + B global loads + X prefetch(kc+1)
// (prefetch issued LAST: vmcnt is FIFO, MFMA's B-wait must not drain it) -> MFMA -> barrier.
__global__ __launch_bounds__(256, 4) void score_top2_kernel(
    const float* __restrict__ x1, const float* __restrict__ x2,
    const unsigned short* __restrict__ Wh, const unsigned short* __restrict__ Wl,
    float* __restrict__ pv, int* __restrict__ pi)
{
    __shared__ __align__(16) char lds[32768];   // Xh @0, Xl @16384; reused for reduction

    const int tid  = threadIdx.x;
    const int nb   = blockIdx.x;   // 0..63
    const int b    = blockIdx.y;   // 0..7
    const int inp  = blockIdx.z;   // 0..1
    const int n0   = nb * TN;
    const float* __restrict__ x = inp ? x2 : x1;
    const float* __restrict__ xbase = x + ((size_t)b * N_ + n0) * F_;

    const int lane = tid & 63;
    const int w    = tid >> 6;       // wave 0..3 = m-tile
    const int rsel = lane & 15;      // row-within-tile (A) / class-within-tile (B)
    const int g    = lane >> 4;      // k-group 0..3
    const int swz  = (rsel & 7) << 4;

    f32x4 acc[4];
    #pragma unroll
    for (int nt = 0; nt < 4; ++nt) acc[nt] = (f32x4){0.f, 0.f, 0.f, 0.f};

    // prologue: load chunk 0 (64 rows x 64 f = 1024 float4, 4 per thread)
    float4 xv[4];
    #pragma unroll
    for (int j = 0; j < 4; ++j) {
        int li = tid + 256 * j, row = li >> 4, fq = li & 15;
        xv[j] = *(const float4*)(xbase + (size_t)row * F_ + fq * 4);
    }

    for (int kc = 0; kc < F_ / KC; ++kc) {
        // ---- convert chunk kc (in xv) to bf16 hi/lo, write swizzled LDS
        #pragma unroll
        for (int j = 0; j < 4; ++j) {
            int li = tid + 256 * j, row = li >> 4, fq = li & 15;
            float f[4] = {xv[j].x, xv[j].y, xv[j].z, xv[j].w};
            us4 hh, ll;
            #pragma unroll
            for (int e = 0; e < 4; ++e) {
                unsigned short h = f2bf_rne(f[e]);
                hh[e] = h;
                ll[e] = f2bf_rne(f[e] - bf2f(h));
            }
            int off = (row * 128 + fq * 8) ^ ((row & 7) << 4);
            *(us4*)(lds + off)         = hh;
            *(us4*)(lds + 16384 + off) = ll;
        }
        __syncthreads();

        // ---- A fragments from LDS (4 x ds_read_b128)
        bhalf8 ah[2], al[2];
        #pragma unroll
        for (int ks = 0; ks < 2; ++ks) {
            int arow = w * 16 + rsel;
            int off = (arow * 128 + ks * 64 + g * 16) ^ swz;
            ah[ks] = *(const bhalf8*)(lds + off);
            al[ks] = *(const bhalf8*)(lds + 16384 + off);
        }
        // ---- B fragments direct from global bf16 planes (L1-resident slice)
        bhalf8 bh[2][4], bl[2][4];
        #pragma unroll
        for (int ks = 0; ks < 2; ++ks)
            #pragma unroll
            for (int nt = 0; nt < 4; ++nt) {
                size_t off = (size_t)(nt * 16 + rsel) * F_ + kc * KC + ks * 32 + g * 8;
                bh[ks][nt] = *(const bhalf8*)(Wh + off);
                bl[ks][nt] = *(const bhalf8*)(Wl + off);
            }
        // ---- prefetch next chunk's X (issued after all B loads; FIFO vmcnt)
        if (kc + 1 < F_ / KC) {
            const int f0 = (kc + 1) * KC;
            #pragma unroll
            for (int j = 0; j < 4; ++j) {
                int li = tid + 256 * j, row = li >> 4, fq = li & 15;
                xv[j] = *(const float4*)(xbase + (size_t)row * F_ + f0 + fq * 4);
            }
        }
        // ---- MFMA: 2 k-steps x 4 n-tiles x 3 split passes
        #pragma unroll
        for (int ks = 0; ks < 2; ++ks)
            #pragma unroll
            for (int nt = 0; nt < 4; ++nt) {
                acc[nt] = __builtin_amdgcn_mfma_f32_16x16x32_bf16(ah[ks], bh[ks][nt], acc[nt], 0, 0, 0);
                acc[nt] = __builtin_amdgcn_mfma_f32_16x16x32_bf16(ah[ks], bl[ks][nt], acc[nt], 0, 0, 0);
                acc[nt] = __builtin_amdgcn_mfma_f32_16x16x32_bf16(al[ks], bh[ks][nt], acc[nt], 0, 0, 0);
            }
        __syncthreads();
    }

    // ---- per-class top-2. D layout: col=lane&15 (class), row=4*(lane>>4)+r.
    float* tv = (float*)lds;            // [4][64][2] floats = 2 KiB
    int*   ti = (int*)(lds + 8192);     // [4][64][2] ints   = 2 KiB
    #pragma unroll
    for (int nt = 0; nt < 4; ++nt) {
        float v0 = -3.4e38f, v1 = -3.4e38f;
        int   i0 = 0x7fffffff, i1 = 0x7fffffff;
        #pragma unroll
        for (int r = 0; r < 4; ++r) {
            int n = n0 + w * 16 + 4 * g + r;
            INSERT2(acc[nt][r], n);
        }
        // merge across the 4 lanes (g=0..3) holding this class
        #pragma unroll
        for (int d = 16; d <= 32; d <<= 1) {
            float u0 = __shfl_xor(v0, d), u1 = __shfl_xor(v1, d);
            int   j0 = __shfl_xor(i0, d), j1 = __shfl_xor(i1, d);
            INSERT2(u0, j0); INSERT2(u1, j1);
        }
        if (lane < 16) {
            int c = nt * 16 + lane;
            tv[(w * C_ + c) * 2 + 0] = v0; tv[(w * C_ + c) * 2 + 1] = v1;
            ti[(w * C_ + c) * 2 + 0] = i0; ti[(w * C_ + c) * 2 + 1] = i1;
        }
    }
    __syncthreads();

    if (tid < C_) {
        int c = tid;
        float v0 = tv[(0 * C_ + c) * 2 + 0], v1 = tv[(0 * C_ + c) * 2 + 1];
        int   i0 = ti[(0 * C_ + c) * 2 + 0], i1 = ti[(0 * C_ + c) * 2 + 1];
        #pragma unroll
        for (int ww = 1; ww < 4; ++ww) {
            INSERT2(tv[(ww * C_ + c) * 2 + 0], ti[(ww * C_ + c) * 2 + 0]);
            INSERT2(tv[(ww * C_ + c) * 2 + 1], ti[(ww * C_ + c) * 2 + 1]);
        }
        int blk = ((inp * B_ + b) * NB + nb);
        pv[(blk * C_ + c) * 2 + 0] = v0; pi[(blk * C_ + c) * 2 + 0] = i0;
        pv[(blk * C_ + c) * 2 + 1] = v1; pi[(blk * C_ + c) * 2 + 1] = i1;
    }
}

// K2: one block per (inp,b,c). Global max over 64 block-top2s, collect
// candidates within MARGIN, exact fp32 dot rescue if >1, gather winning row.
__global__ __launch_bounds__(256) void select_gather_kernel(
    const float* __restrict__ x1, const float* __restrict__ x2,
    const float* __restrict__ W,
    const float* __restrict__ pv, const int* __restrict__ pi,
    float* __restrict__ out)
{
    const int c   = blockIdx.x;    // 0..63
    const int b   = blockIdx.y;    // 0..7
    const int inp = blockIdx.z;    // 0..1
    const int tid = threadIdx.x;

    __shared__ int   s_cnt;
    __shared__ int   s_cand[8];
    __shared__ float s_val[8];
    __shared__ float s_wsum[4];
    __shared__ int   s_win;

    if (tid == 0) s_cnt = 0;
    __syncthreads();

    if (tid < 64) {
        int blk = ((inp * B_ + b) * NB + tid);
        float m = pv[(blk * C_ + c) * 2 + 0];          // block max (entry 0)
        #pragma unroll
        for (int d = 32; d; d >>= 1) m = fmaxf(m, __shfl_xor(m, d));
        #pragma unroll
        for (int k = 0; k < 2; ++k) {
            float v = pv[(blk * C_ + c) * 2 + k];
            if (v >= m - MARGIN) {
                int p = atomicAdd(&s_cnt, 1);
                if (p < 8) s_cand[p] = pi[(blk * C_ + c) * 2 + k];
            }
        }
    }
    __syncthreads();

    const float* __restrict__ x = inp ? x2 : x1;
    const int ncand = min(s_cnt, 8);
    int winner;
    if (ncand == 1) {
        winner = s_cand[0];
    } else {
        for (int k = 0; k < ncand; ++k) {
            int n = s_cand[k];
            float4 xv = *(const float4*)(x + ((size_t)b * N_ + n) * F_ + tid * 4);
            float4 wv = *(const float4*)(W + (size_t)c * F_ + tid * 4);
            float p = xv.x * wv.x + xv.y * wv.y + xv.z * wv.z + xv.w * wv.w;
            #pragma unroll
            for (int d = 32; d; d >>= 1) p += __shfl_down(p, d);
            if ((tid & 63) == 0) s_wsum[tid >> 6] = p;
            __syncthreads();
            if (tid == 0) s_val[k] = s_wsum[0] + s_wsum[1] + s_wsum[2] + s_wsum[3];
            __syncthreads();
        }
        if (tid == 0) {
            float bv = s_val[0]; int bn = s_cand[0];
            for (int k = 1; k < ncand; ++k)
                if (s_val[k] > bv || (s_val[k] == bv && s_cand[k] < bn)) { bv = s_val[k]; bn = s_cand[k]; }
            s_win = bn;
        }
        __syncthreads();
        winner = s_win;
    }

    float4 v = *(const float4*)(x + ((size_t)b * N_ + winner) * F_ + tid * 4);
    *(float4*)(out + (((size_t)inp * B_ + b) * C_ + c) * F_ + tid * 4) = v;
}

extern "C" void kernel_launch(void* const* d_in, const int* in_sizes, int n_in,
                              void* d_out, int out_size, void* d_ws, size_t ws_size,
                              hipStream_t stream) {
    const float* x1 = (const float*)d_in[0];
    const float* x2 = (const float*)d_in[1];
    const float* W  = (const float*)d_in[2];
    // d_in[3] (bias) is constant per class -> cannot change the argmax. Skipped.

    // ws layout: Wh (128 KiB) | Wl (128 KiB) | pv (512 KiB) | pi (512 KiB)
    unsigned short* Wh = (unsigned short*)d_ws;
    unsigned short* Wl = Wh + (size_t)C_ * F_;
    float* pv = (float*)((char*)d_ws + 2 * (size_t)C_ * F_ * sizeof(unsigned short));
    int*   pi = (int*)((char*)pv + (size_t)2 * B_ * NB * C_ * 2 * sizeof(float));

    wconv_kernel<<<C_ * F_ / 1024, 256, 0, stream>>>(W, Wh, Wl);
    dim3 g1(NB, B_, 2);
    score_top2_kernel<<<g1, 256, 0, stream>>>(x1, x2, Wh, Wl, pv, pi);
    dim3 g2(C_, B_, 2);
    select_gather_kernel<<<g2, 256, 0, stream>>>(x1, x2, W, pv, pi, (float*)d_out);
}

// Round 4
// 78.248 us; speedup vs baseline: 1.8549x; 1.8549x over previous
//
#include <hip/hip_runtime.h>

// Problem constants (reference: B=8, N=4096, F=1024, C=64)
#define B_   8
#define N_   4096
#define F_   1024
#define C_   64
#define MARGIN 0.08f   // hi-only bf16 score error sigma ~3e-3; 0.08 ~ 18 sigma on diffs

typedef __attribute__((ext_vector_type(8))) short bhalf8;   // 8 bf16 (MFMA A/B frag)
typedef __attribute__((ext_vector_type(4))) float f32x4;    // MFMA C/D frag

__device__ __forceinline__ unsigned short f2bf_rne(float x) {
    unsigned u = __builtin_bit_cast(unsigned, x);
    u += 0x7fffu + ((u >> 16) & 1u);          // round-to-nearest-even
    return (unsigned short)(u >> 16);
}
__device__ __forceinline__ bhalf8 cvt8(float4 a, float4 b) {
    bhalf8 r;
    r[0] = (short)f2bf_rne(a.x); r[1] = (short)f2bf_rne(a.y);
    r[2] = (short)f2bf_rne(a.z); r[3] = (short)f2bf_rne(a.w);
    r[4] = (short)f2bf_rne(b.x); r[5] = (short)f2bf_rne(b.y);
    r[6] = (short)f2bf_rne(b.z); r[7] = (short)f2bf_rne(b.w);
    return r;
}

#define LEXGT(a, ai, b, bi) ((a) > (b) || ((a) == (b) && (ai) < (bi)))
#define INSERT3(vv, nn)                                                        \
    do {                                                                       \
        float _v = (vv); int _n = (nn);                                        \
        if (LEXGT(_v, _n, v0, i0)) { v2=v1; i2=i1; v1=v0; i1=i0; v0=_v; i0=_n; } \
        else if (LEXGT(_v, _n, v1, i1)) { v2=v1; i2=i1; v1=_v; i1=_n; }        \
        else if (LEXGT(_v, _n, v2, i2)) { v2=_v; i2=_n; }                      \
    } while (0)
#define INSERT4(vv, nn)                                                        \
    do {                                                                       \
        float _v = (vv); int _n = (nn);                                        \
        if (LEXGT(_v, _n, v0, i0)) { v3=v2; i3=i2; v2=v1; i2=i1; v1=v0; i1=i0; v0=_v; i0=_n; } \
        else if (LEXGT(_v, _n, v1, i1)) { v3=v2; i3=i2; v2=v1; i2=i1; v1=_v; i1=_n; } \
        else if (LEXGT(_v, _n, v2, i2)) { v3=v2; i3=i2; v2=_v; i2=_n; }        \
        else if (LEXGT(_v, _n, v3, i3)) { v3=_v; i3=_n; }                      \
    } while (0)

// K1: hi-only bf16 MFMA scores, streaming X global->reg->MFMA (no X LDS, no
// main-loop barriers). W (fp32 [64][1024]) converted to bf16 and staged in
// 128 KiB LDS ONCE at kernel start, XOR-swizzled (^((c&7)<<4)) so the per-
// K-step ds_read_b128 of 16 class-rows at one k-column is bank-conflict-free.
// Block: 512 thr = 8 waves, each wave owns 16 rows x 64 classes over full K.
// Per K=64 chunk/wave: 4x float4 global (reg double-buffered), 2x(cvt8 +
// 4 ds_read_b128 + 4 MFMA). Fused per-wave top-3 -> per-block top-4 per class.
__global__ __launch_bounds__(512, 2) void score_top_kernel(
    const float* __restrict__ x1, const float* __restrict__ x2,
    const float* __restrict__ W,
    float* __restrict__ pv, int* __restrict__ pi)
{
    __shared__ __align__(16) char lds[131072];  // W bf16 [64][2048B] swizzled; reused for reduction

    const int tid  = threadIdx.x;
    const int nb   = blockIdx.x;   // 0..31 (128-row group)
    const int b    = blockIdx.y;   // 0..7
    const int inp  = blockIdx.z;   // 0..1
    const float* __restrict__ x = inp ? x2 : x1;

    const int lane = tid & 63;
    const int w    = tid >> 6;       // wave 0..7
    const int rsel = lane & 15;
    const int g    = lane >> 4;      // 0..3
    const int swz  = (rsel & 7) << 4;

    // ---- stage W -> bf16 LDS (once). 8192 bhalf8 groups, 16 per thread.
    #pragma unroll
    for (int j = 0; j < 16; ++j) {
        int gi = tid + 512 * j;
        int c = gi >> 7, kq = gi & 127;
        const float* src = W + (size_t)c * F_ + kq * 8;
        float4 a  = *(const float4*)src;
        float4 bq = *(const float4*)(src + 4);
        int off = (c * 2048 + kq * 16) ^ ((c & 7) << 4);
        *(bhalf8*)(lds + off) = cvt8(a, bq);
    }

    const int row = nb * 128 + w * 16 + rsel;
    const float* __restrict__ xr = x + ((size_t)b * N_ + row) * F_ + g * 8;

    f32x4 acc[4];
    #pragma unroll
    for (int nt = 0; nt < 4; ++nt) acc[nt] = (f32x4){0.f, 0.f, 0.f, 0.f};

    auto loadx = [&](float4* dst, int kc) {
        #pragma unroll
        for (int st = 0; st < 2; ++st) {
            dst[2 * st]     = *(const float4*)(xr + kc * 64 + st * 32);
            dst[2 * st + 1] = *(const float4*)(xr + kc * 64 + st * 32 + 4);
        }
    };
    auto compute = [&](const float4* src, int kc) {
        #pragma unroll
        for (int st = 0; st < 2; ++st) {
            bhalf8 ah = cvt8(src[2 * st], src[2 * st + 1]);
            int kb = (kc * 64 + st * 32 + g * 8) * 2;
            #pragma unroll
            for (int nt = 0; nt < 4; ++nt) {
                int cls = nt * 16 + rsel;
                bhalf8 bf = *(const bhalf8*)(lds + ((cls * 2048 + kb) ^ swz));
                acc[nt] = __builtin_amdgcn_mfma_f32_16x16x32_bf16(ah, bf, acc[nt], 0, 0, 0);
            }
        }
    };

    float4 xa[4], xb[4];
    loadx(xa, 0);
    __syncthreads();                 // W staged (also drains xa; once, ok)

    #pragma unroll
    for (int kc = 0; kc < 16; kc += 2) {
        loadx(xb, kc + 1);           // prefetch next chunk while computing current
        compute(xa, kc);
        if (kc + 2 < 16) loadx(xa, kc + 2);
        compute(xb, kc + 1);
    }

    // ---- per-wave top-3 per class (registers + shfl only; no LDS yet)
    float wv0[4], wv1[4], wv2[4]; int wi0[4], wi1[4], wi2[4];
    #pragma unroll
    for (int nt = 0; nt < 4; ++nt) {
        float v0 = -3.4e38f, v1 = -3.4e38f, v2 = -3.4e38f;
        int   i0 = 0x7fffffff, i1 = 0x7fffffff, i2 = 0x7fffffff;
        #pragma unroll
        for (int r = 0; r < 4; ++r) {
            int n = nb * 128 + w * 16 + 4 * g + r;   // D layout: row = 4g+r
            INSERT3(acc[nt][r], n);
        }
        #pragma unroll
        for (int d = 16; d <= 32; d <<= 1) {
            float u0 = __shfl_xor(v0, d), u1 = __shfl_xor(v1, d), u2 = __shfl_xor(v2, d);
            int   j0 = __shfl_xor(i0, d), j1 = __shfl_xor(i1, d), j2 = __shfl_xor(i2, d);
            INSERT3(u0, j0); INSERT3(u1, j1); INSERT3(u2, j2);
        }
        wv0[nt] = v0; wv1[nt] = v1; wv2[nt] = v2;
        wi0[nt] = i0; wi1[nt] = i1; wi2[nt] = i2;
    }

    __syncthreads();                 // all waves done reading W -> safe to alias LDS
    float* tv = (float*)lds;                   // [8][64][3] = 6 KiB
    int*   ti = (int*)(lds + 6144);            // [8][64][3] = 6 KiB
    if (lane < 16) {
        #pragma unroll
        for (int nt = 0; nt < 4; ++nt) {
            int c = nt * 16 + lane;
            tv[(w * C_ + c) * 3 + 0] = wv0[nt]; ti[(w * C_ + c) * 3 + 0] = wi0[nt];
            tv[(w * C_ + c) * 3 + 1] = wv1[nt]; ti[(w * C_ + c) * 3 + 1] = wi1[nt];
            tv[(w * C_ + c) * 3 + 2] = wv2[nt]; ti[(w * C_ + c) * 3 + 2] = wi2[nt];
        }
    }
    __syncthreads();

    // ---- block top-4 per class, write partials
    if (tid < C_) {
        int c = tid;
        float v0 = -3.4e38f, v1 = -3.4e38f, v2 = -3.4e38f, v3 = -3.4e38f;
        int   i0 = 0x7fffffff, i1 = 0x7fffffff, i2 = 0x7fffffff, i3 = 0x7fffffff;
        #pragma unroll
        for (int ww = 0; ww < 8; ++ww)
            #pragma unroll
            for (int k = 0; k < 3; ++k)
                INSERT4(tv[(ww * C_ + c) * 3 + k], ti[(ww * C_ + c) * 3 + k]);
        int blk = ((inp * B_ + b) * 32 + nb);
        pv[(blk * C_ + c) * 4 + 0] = v0; pi[(blk * C_ + c) * 4 + 0] = i0;
        pv[(blk * C_ + c) * 4 + 1] = v1; pi[(blk * C_ + c) * 4 + 1] = i1;
        pv[(blk * C_ + c) * 4 + 2] = v2; pi[(blk * C_ + c) * 4 + 2] = i2;
        pv[(blk * C_ + c) * 4 + 3] = v3; pi[(blk * C_ + c) * 4 + 3] = i3;
    }
}

// K2: one block per (inp,b,c). Max over 32 block-top4s (128 entries), collect
// candidates within MARGIN, exact fp32 dot rescue if >1, gather winning row.
__global__ __launch_bounds__(256) void select_gather_kernel(
    const float* __restrict__ x1, const float* __restrict__ x2,
    const float* __restrict__ W,
    const float* __restrict__ pv, const int* __restrict__ pi,
    float* __restrict__ out)
{
    const int c   = blockIdx.x;    // 0..63
    const int b   = blockIdx.y;    // 0..7
    const int inp = blockIdx.z;    // 0..1
    const int tid = threadIdx.x;

    __shared__ int   s_cnt;
    __shared__ float s_m[2];
    __shared__ int   s_cand[16];
    __shared__ float s_val[16];
    __shared__ float s_wsum[4];
    __shared__ int   s_win;

    if (tid == 0) s_cnt = 0;
    __syncthreads();

    float v = -3.4e38f;
    int myoff = 0;
    if (tid < 128) {
        int nb = tid >> 2, k = tid & 3;
        int blk = ((inp * B_ + b) * 32 + nb);
        myoff = (blk * C_ + c) * 4 + k;
        v = pv[myoff];
    }
    {   // per-wave max (waves 0-1 hold the 128 entries)
        float m = v;
        #pragma unroll
        for (int d = 32; d; d >>= 1) m = fmaxf(m, __shfl_xor(m, d));
        if ((tid & 63) == 0 && tid < 128) s_m[tid >> 6] = m;
    }
    __syncthreads();
    const float m = fmaxf(s_m[0], s_m[1]);
    if (tid < 128 && v >= m - MARGIN) {
        int p = atomicAdd(&s_cnt, 1);
        if (p < 16) s_cand[p] = pi[myoff];
    }
    __syncthreads();

    const float* __restrict__ x = inp ? x2 : x1;
    const int ncand = min(s_cnt, 16);
    int winner;
    if (ncand == 1) {
        winner = s_cand[0];
    } else {
        for (int k = 0; k < ncand; ++k) {
            int n = s_cand[k];
            float4 xv = *(const float4*)(x + ((size_t)b * N_ + n) * F_ + tid * 4);
            float4 wq = *(const float4*)(W + (size_t)c * F_ + tid * 4);
            float p = xv.x * wq.x + xv.y * wq.y + xv.z * wq.z + xv.w * wq.w;
            #pragma unroll
            for (int d = 32; d; d >>= 1) p += __shfl_down(p, d);
            if ((tid & 63) == 0) s_wsum[tid >> 6] = p;
            __syncthreads();
            if (tid == 0) s_val[k] = s_wsum[0] + s_wsum[1] + s_wsum[2] + s_wsum[3];
            __syncthreads();
        }
        if (tid == 0) {
            float bv = s_val[0]; int bn = s_cand[0];
            for (int k = 1; k < ncand; ++k)
                if (s_val[k] > bv || (s_val[k] == bv && s_cand[k] < bn)) { bv = s_val[k]; bn = s_cand[k]; }
            s_win = bn;
        }
        __syncthreads();
        winner = s_win;
    }

    float4 vv = *(const float4*)(x + ((size_t)b * N_ + winner) * F_ + tid * 4);
    *(float4*)(out + (((size_t)inp * B_ + b) * C_ + c) * F_ + tid * 4) = vv;
}

extern "C" void kernel_launch(void* const* d_in, const int* in_sizes, int n_in,
                              void* d_out, int out_size, void* d_ws, size_t ws_size,
                              hipStream_t stream) {
    const float* x1 = (const float*)d_in[0];
    const float* x2 = (const float*)d_in[1];
    const float* W  = (const float*)d_in[2];
    // d_in[3] (bias) is constant per class -> cannot change the argmax. Skipped.

    // ws: pv [512][64][4] f32 = 512 KiB | pi same = 512 KiB
    float* pv = (float*)d_ws;
    int*   pi = (int*)((char*)d_ws + (size_t)2 * B_ * 32 * C_ * 4 * sizeof(float));

    dim3 g1(32, B_, 2);
    score_top_kernel<<<g1, 512, 0, stream>>>(x1, x2, W, pv, pi);
    dim3 g2(C_, B_, 2);
    select_gather_kernel<<<g2, 256, 0, stream>>>(x1, x2, W, pv, pi, (float*)d_out);
}

// Round 5
// 72.491 us; speedup vs baseline: 2.0022x; 1.0794x over previous
//
#include <hip/hip_runtime.h>

// Problem constants (reference: B=8, N=4096, F=1024, C=64)
#define B_   8
#define N_   4096
#define F_   1024
#define C_   64
#define NBLK 16        // row-groups of 256 per (inp,b)
#define MARGIN 0.08f   // hi-only bf16 score error sigma ~6e-3; 0.08 ~ 10 sigma on diffs

typedef __attribute__((ext_vector_type(8))) short bhalf8;   // 8 bf16 (MFMA A/B frag)
typedef __attribute__((ext_vector_type(4))) float f32x4;    // MFMA C/D frag
typedef __attribute__((ext_vector_type(4))) unsigned short us4;

__device__ __forceinline__ unsigned short f2bf_rne(float x) {
    unsigned u = __builtin_bit_cast(unsigned, x);
    u += 0x7fffu + ((u >> 16) & 1u);          // round-to-nearest-even
    return (unsigned short)(u >> 16);
}
__device__ __forceinline__ bhalf8 cvt8(float4 a, float4 b) {
    bhalf8 r;
    r[0] = (short)f2bf_rne(a.x); r[1] = (short)f2bf_rne(a.y);
    r[2] = (short)f2bf_rne(a.z); r[3] = (short)f2bf_rne(a.w);
    r[4] = (short)f2bf_rne(b.x); r[5] = (short)f2bf_rne(b.y);
    r[6] = (short)f2bf_rne(b.z); r[7] = (short)f2bf_rne(b.w);
    return r;
}

#define LEXGT(a, ai, b, bi) ((a) > (b) || ((a) == (b) && (ai) < (bi)))
#define INSERT3(vv, nn)                                                        \
    do {                                                                       \
        float _v = (vv); int _n = (nn);                                        \
        if (LEXGT(_v, _n, v0, i0)) { v2=v1; i2=i1; v1=v0; i1=i0; v0=_v; i0=_n; } \
        else if (LEXGT(_v, _n, v1, i1)) { v2=v1; i2=i1; v1=_v; i1=_n; }        \
        else if (LEXGT(_v, _n, v2, i2)) { v2=_v; i2=_n; }                      \
    } while (0)
#define INSERT4(vv, nn)                                                        \
    do {                                                                       \
        float _v = (vv); int _n = (nn);                                        \
        if (LEXGT(_v, _n, v0, i0)) { v3=v2; i3=i2; v2=v1; i2=i1; v1=v0; i1=i0; v0=_v; i0=_n; } \
        else if (LEXGT(_v, _n, v1, i1)) { v3=v2; i3=i2; v2=v1; i2=i1; v1=_v; i1=_n; } \
        else if (LEXGT(_v, _n, v2, i2)) { v3=v2; i3=i2; v2=_v; i2=_n; }        \
        else if (LEXGT(_v, _n, v3, i3)) { v3=_v; i3=_n; }                      \
    } while (0)

// K0: convert W (fp32 [64][1024]) to bf16 (hi only) in workspace.
__global__ __launch_bounds__(256) void wconv_kernel(
    const float* __restrict__ W, unsigned short* __restrict__ Wh)
{
    int i = blockIdx.x * 256 + threadIdx.x;        // 16384 float4s total
    float4 v = ((const float4*)W)[i];
    us4 hh;
    hh[0] = f2bf_rne(v.x); hh[1] = f2bf_rne(v.y);
    hh[2] = f2bf_rne(v.z); hh[3] = f2bf_rne(v.w);
    ((us4*)Wh)[i] = hh;
}

// K1: hi-only bf16 MFMA scores, streaming X global->reg->cvt->MFMA.
// 1024 threads = 16 waves, grid 256 = 1 block/CU (4 waves/SIMD).
// W bf16 staged once into 128 KiB LDS (XOR-swizzled ^((c&7)<<4)).
// Each wave owns 16 rows x 64 classes over full K=1024; K chunked at 128
// (8 chunks), register double-buffered (8 float4 per buffer) -> ~400cy
// compute per chunk, x4 waves/SIMD covers HBM latency; no main-loop barriers.
// Fused per-wave top-3 -> per-block top-4 per class.
__global__ __launch_bounds__(1024, 4) void score_top_kernel(
    const float* __restrict__ x1, const float* __restrict__ x2,
    const unsigned short* __restrict__ Wh,
    float* __restrict__ pv, int* __restrict__ pi)
{
    __shared__ __align__(16) char lds[131072];  // W bf16 [64][2048B] swizzled; reused for reduction

    const int tid  = threadIdx.x;
    const int nb   = blockIdx.x;   // 0..15 (256-row group)
    const int b    = blockIdx.y;   // 0..7
    const int inp  = blockIdx.z;   // 0..1
    const float* __restrict__ x = inp ? x2 : x1;

    const int lane = tid & 63;
    const int w    = tid >> 6;       // wave 0..15
    const int rsel = lane & 15;
    const int g    = lane >> 4;      // 0..3
    const int swz  = (rsel & 7) << 4;

    const int row = nb * 256 + w * 16 + rsel;
    const float* __restrict__ xr = x + ((size_t)b * N_ + row) * F_ + g * 8;

    f32x4 acc[4];
    #pragma unroll
    for (int nt = 0; nt < 4; ++nt) acc[nt] = (f32x4){0.f, 0.f, 0.f, 0.f};

    auto loadx = [&](float4* dst, int kc) {      // 128 floats of this lane's row-slice
        #pragma unroll
        for (int st = 0; st < 4; ++st) {
            dst[2 * st]     = *(const float4*)(xr + kc * 128 + st * 32);
            dst[2 * st + 1] = *(const float4*)(xr + kc * 128 + st * 32 + 4);
        }
    };
    auto compute = [&](const float4* src, int kc) {
        #pragma unroll
        for (int st = 0; st < 4; ++st) {
            bhalf8 ah = cvt8(src[2 * st], src[2 * st + 1]);
            int kb = kc * 256 + st * 64 + g * 16;          // byte offset within W row
            #pragma unroll
            for (int nt = 0; nt < 4; ++nt) {
                int cls = nt * 16 + rsel;
                bhalf8 bf = *(const bhalf8*)(lds + ((cls * 2048 + kb) ^ swz));
                acc[nt] = __builtin_amdgcn_mfma_f32_16x16x32_bf16(ah, bf, acc[nt], 0, 0, 0);
            }
        }
    };

    float4 xa[8], xb[8];
    loadx(xa, 0);                                // start the X stream first

    // ---- stage W bf16 -> LDS (once per block). 8192 x 16B, 8 per thread.
    #pragma unroll
    for (int j = 0; j < 8; ++j) {
        int gi = tid + 1024 * j;
        int c = gi >> 7, kq = gi & 127;
        bhalf8 v = *(const bhalf8*)(Wh + (size_t)c * F_ + kq * 8);
        *(bhalf8*)(lds + ((c * 2048 + kq * 16) ^ ((c & 7) << 4))) = v;
    }
    __syncthreads();

    #pragma unroll
    for (int kc = 0; kc < 8; kc += 2) {
        loadx(xb, kc + 1);                       // prefetch while computing current
        compute(xa, kc);
        if (kc + 2 < 8) loadx(xa, kc + 2);
        compute(xb, kc + 1);
    }

    // ---- per-wave top-3 per class (registers + shfl only)
    float wv0[4], wv1[4], wv2[4]; int wi0[4], wi1[4], wi2[4];
    #pragma unroll
    for (int nt = 0; nt < 4; ++nt) {
        float v0 = -3.4e38f, v1 = -3.4e38f, v2 = -3.4e38f;
        int   i0 = 0x7fffffff, i1 = 0x7fffffff, i2 = 0x7fffffff;
        #pragma unroll
        for (int r = 0; r < 4; ++r) {
            int n = nb * 256 + w * 16 + 4 * g + r;   // D layout: row = 4g+r
            INSERT3(acc[nt][r], n);
        }
        #pragma unroll
        for (int d = 16; d <= 32; d <<= 1) {
            float u0 = __shfl_xor(v0, d), u1 = __shfl_xor(v1, d), u2 = __shfl_xor(v2, d);
            int   j0 = __shfl_xor(i0, d), j1 = __shfl_xor(i1, d), j2 = __shfl_xor(i2, d);
            INSERT3(u0, j0); INSERT3(u1, j1); INSERT3(u2, j2);
        }
        wv0[nt] = v0; wv1[nt] = v1; wv2[nt] = v2;
        wi0[nt] = i0; wi1[nt] = i1; wi2[nt] = i2;
    }

    __syncthreads();                 // all waves done reading W -> safe to alias LDS
    float* tv = (float*)lds;                   // [16][64][3] = 12 KiB
    int*   ti = (int*)(lds + 16384);           // [16][64][3] = 12 KiB
    if (lane < 16) {
        #pragma unroll
        for (int nt = 0; nt < 4; ++nt) {
            int c = nt * 16 + lane;
            tv[(w * C_ + c) * 3 + 0] = wv0[nt]; ti[(w * C_ + c) * 3 + 0] = wi0[nt];
            tv[(w * C_ + c) * 3 + 1] = wv1[nt]; ti[(w * C_ + c) * 3 + 1] = wi1[nt];
            tv[(w * C_ + c) * 3 + 2] = wv2[nt]; ti[(w * C_ + c) * 3 + 2] = wi2[nt];
        }
    }
    __syncthreads();

    // ---- block top-4 per class over 16 waves x 3, write partials
    if (tid < C_) {
        int c = tid;
        float v0 = -3.4e38f, v1 = -3.4e38f, v2 = -3.4e38f, v3 = -3.4e38f;
        int   i0 = 0x7fffffff, i1 = 0x7fffffff, i2 = 0x7fffffff, i3 = 0x7fffffff;
        #pragma unroll 4
        for (int ww = 0; ww < 16; ++ww)
            #pragma unroll
            for (int k = 0; k < 3; ++k)
                INSERT4(tv[(ww * C_ + c) * 3 + k], ti[(ww * C_ + c) * 3 + k]);
        int blk = ((inp * B_ + b) * NBLK + nb);
        pv[(blk * C_ + c) * 4 + 0] = v0; pi[(blk * C_ + c) * 4 + 0] = i0;
        pv[(blk * C_ + c) * 4 + 1] = v1; pi[(blk * C_ + c) * 4 + 1] = i1;
        pv[(blk * C_ + c) * 4 + 2] = v2; pi[(blk * C_ + c) * 4 + 2] = i2;
        pv[(blk * C_ + c) * 4 + 3] = v3; pi[(blk * C_ + c) * 4 + 3] = i3;
    }
}

// K2: one block per (inp,b,c). Max over 16 block-top4s (64 entries, one wave),
// collect candidates within MARGIN, exact fp32 dot rescue if >1, gather row.
__global__ __launch_bounds__(256) void select_gather_kernel(
    const float* __restrict__ x1, const float* __restrict__ x2,
    const float* __restrict__ W,
    const float* __restrict__ pv, const int* __restrict__ pi,
    float* __restrict__ out)
{
    const int c   = blockIdx.x;    // 0..63
    const int b   = blockIdx.y;    // 0..7
    const int inp = blockIdx.z;    // 0..1
    const int tid = threadIdx.x;

    __shared__ int   s_cnt;
    __shared__ float s_m;
    __shared__ int   s_cand[16];
    __shared__ float s_val[16];
    __shared__ float s_wsum[4];
    __shared__ int   s_win;

    if (tid == 0) s_cnt = 0;
    __syncthreads();

    if (tid < 64) {                 // exactly wave 0
        int nb = tid >> 2, k = tid & 3;
        int blk = ((inp * B_ + b) * NBLK + nb);
        int myoff = (blk * C_ + c) * 4 + k;
        float v = pv[myoff];
        float m = v;
        #pragma unroll
        for (int d = 32; d; d >>= 1) m = fmaxf(m, __shfl_xor(m, d));
        if (tid == 0) s_m = m;
        if (v >= m - MARGIN) {
            int p = atomicAdd(&s_cnt, 1);
            if (p < 16) s_cand[p] = pi[myoff];
        }
    }
    __syncthreads();

    const float* __restrict__ x = inp ? x2 : x1;
    const int ncand = min(s_cnt, 16);
    int winner;
    if (ncand == 1) {
        winner = s_cand[0];
    } else {
        for (int k = 0; k < ncand; ++k) {
            int n = s_cand[k];
            float4 xv = *(const float4*)(x + ((size_t)b * N_ + n) * F_ + tid * 4);
            float4 wq = *(const float4*)(W + (size_t)c * F_ + tid * 4);
            float p = xv.x * wq.x + xv.y * wq.y + xv.z * wq.z + xv.w * wq.w;
            #pragma unroll
            for (int d = 32; d; d >>= 1) p += __shfl_down(p, d);
            if ((tid & 63) == 0) s_wsum[tid >> 6] = p;
            __syncthreads();
            if (tid == 0) s_val[k] = s_wsum[0] + s_wsum[1] + s_wsum[2] + s_wsum[3];
            __syncthreads();
        }
        if (tid == 0) {
            float bv = s_val[0]; int bn = s_cand[0];
            for (int k = 1; k < ncand; ++k)
                if (s_val[k] > bv || (s_val[k] == bv && s_cand[k] < bn)) { bv = s_val[k]; bn = s_cand[k]; }
            s_win = bn;
        }
        __syncthreads();
        winner = s_win;
    }

    float4 vv = *(const float4*)(x + ((size_t)b * N_ + winner) * F_ + tid * 4);
    *(float4*)(out + (((size_t)inp * B_ + b) * C_ + c) * F_ + tid * 4) = vv;
}

extern "C" void kernel_launch(void* const* d_in, const int* in_sizes, int n_in,
                              void* d_out, int out_size, void* d_ws, size_t ws_size,
                              hipStream_t stream) {
    const float* x1 = (const float*)d_in[0];
    const float* x2 = (const float*)d_in[1];
    const float* W  = (const float*)d_in[2];
    // d_in[3] (bias) is constant per class -> cannot change the argmax. Skipped.

    // ws: Wh bf16 [64][1024] = 128 KiB | pv [256][64][4] f32 = 256 KiB | pi = 256 KiB
    unsigned short* Wh = (unsigned short*)d_ws;
    float* pv = (float*)((char*)d_ws + (size_t)C_ * F_ * sizeof(unsigned short));
    int*   pi = (int*)((char*)pv + (size_t)2 * B_ * NBLK * C_ * 4 * sizeof(float));

    wconv_kernel<<<C_ * F_ / 1024, 256, 0, stream>>>(W, Wh);
    dim3 g1(NBLK, B_, 2);
    score_top_kernel<<<g1, 1024, 0, stream>>>(x1, x2, Wh, pv, pi);
    dim3 g2(C_, B_, 2);
    select_gather_kernel<<<g2, 256, 0, stream>>>(x1, x2, W, pv, pi, (float*)d_out);
}